// Round 1
// baseline (195.920 us; speedup 1.0000x reference)
//
#include <hip/hip_runtime.h>
#include <hip/hip_cooperative_groups.h>

namespace cg = cooperative_groups;

#define N_FFT 4096
#define NH    2048          // N_FFT/2 (complex FFT length)
#define NBINS 2049          // N_FFT/2 + 1
#define NLAGS 81            // 2*MAX_TAU + 1
#define MAXTAU 40
#define NSEG  8             // (fallback kernel) k-segments per (b,p) pair
#define SEGLEN 256
#define PI_F 3.14159265358979323846f
#define PAD(i) ((i) + ((i) >> 4))   // LDS bank-conflict padding (+1 per 16)

// e^{-2*pi*i/4096} as f32 constants (cos, sin)
#define CQ 0.99999882345f
#define SQ 0.00153398019f

// mega-kernel DFT chunking: 41 lags x 12 chunks of ceil(2049/12)=171 bins
#define NCHK 12
#define CHLEN 171
#define NBLOCKS 256

__device__ __forceinline__ float2 cmul(float2 a, float2 b) {
    return make_float2(a.x * b.x - a.y * b.y, a.x * b.y + a.y * b.x);
}

// ===========================================================================
// MEGA KERNEL (cooperative launch, single dispatch).
// Phase 1: rfft per channel -> S        (blocks 0..BM-1)
// Phase 2: PHAT + 81-lag DFT -> cc      (1 block per (b,p): no atomics)
// Phase 3: power + argmax -> packed u64 atomicMax per batch
// Phase 4: decode winner -> out
// Cross-block deps only via grid.sync() (sanctioned mechanism).
// ===========================================================================
__global__ __launch_bounds__(512)
void mega_kernel(const float* __restrict__ sig,
                 const int* __restrict__ comb,
                 const int* __restrict__ tau,
                 const float* __restrict__ grid_x,
                 const float* __restrict__ rec_centroid,
                 float* __restrict__ out,
                 float* __restrict__ S,
                 float* __restrict__ cc,
                 unsigned long long* __restrict__ packed,
                 int BM, int P, int B, int G, int nchunks) {
    cg::grid_group gg = cg::this_grid();
    const int bid = (int)blockIdx.x;
    const int tid = (int)threadIdx.x;
    const int nb  = (int)gridDim.x;

    __shared__ __align__(16) float2 data[PAD(NH - 1) + 1]; // 17.4 KB; aliased below
    __shared__ float2 tw[NH / 2];                          //  8 KB
    __shared__ float partCr[41 * NCHK];                    //  ~2 KB
    __shared__ float partCi[41 * NCHK];
    __shared__ float wval[8];
    __shared__ int   widx[8];

    // zero the per-batch argmax slots (workspace is poisoned each iteration);
    // two grid.sync()s separate this from first use in phase 3.
    if (bid == nb - 1 && tid < B) packed[tid] = 0ull;

    // ------------------------- Phase 1: rfft ------------------------------
    // twiddle table (only FFT-active blocks need it)
    if (bid < BM) {
        for (int j = tid; j < NH / 2; j += 512) {
            float sv, cv;
            sincosf(-(2.0f * PI_F / (float)NH) * (float)j, &sv, &cv);
            tw[j] = make_float2(cv, sv);
        }
    }
    for (int ch = bid; ch < BM; ch += nb) {
        // load packed real pairs, scatter to bit-reversed position
        const float2* sp = (const float2*)(sig + (size_t)ch * N_FFT);
        for (int i = tid; i < NH; i += 512) {
            float2 v = sp[i];
            int j = (int)(__brev((unsigned)i) >> 21);   // 11-bit reverse
            data[PAD(j)] = v;
        }
        __syncthreads();

        // stages 1..10 as 5 combined passes (two radix-2 levels per barrier)
        for (int s = 1; s <= 9; s += 2) {
            int h  = 1 << (s - 1);
            int j  = tid & (h - 1);
            int g  = tid >> (s - 1);
            int i0 = (g << (s + 1)) + j;
            int i1 = i0 + h, i2 = i0 + 2 * h, i3 = i0 + 3 * h;

            float2 w1 = tw[j << (11 - s)];
            float2 wA = tw[j << (10 - s)];
            float2 wB = tw[(j + h) << (10 - s)];

            float2 a = data[PAD(i0)];
            float2 b = data[PAD(i1)];
            float2 c = data[PAD(i2)];
            float2 d = data[PAD(i3)];

            float2 wb = cmul(w1, b), wd = cmul(w1, d);
            float2 a1 = make_float2(a.x + wb.x, a.y + wb.y);
            float2 b1 = make_float2(a.x - wb.x, a.y - wb.y);
            float2 c1 = make_float2(c.x + wd.x, c.y + wd.y);
            float2 d1 = make_float2(c.x - wd.x, c.y - wd.y);
            float2 wc = cmul(wA, c1), wdd = cmul(wB, d1);
            data[PAD(i0)] = make_float2(a1.x + wc.x,  a1.y + wc.y);
            data[PAD(i2)] = make_float2(a1.x - wc.x,  a1.y - wc.y);
            data[PAD(i1)] = make_float2(b1.x + wdd.x, b1.y + wdd.y);
            data[PAD(i3)] = make_float2(b1.x - wdd.x, b1.y - wdd.y);
            __syncthreads();
        }

        // stage 11 (half = 1024): 1024 butterflies, 2 per thread
        for (int t = tid; t < 1024; t += 512) {
            int i0 = t, i1 = t + 1024;
            float2 w = tw[t];
            float2 u = data[PAD(i0)];
            float2 v = data[PAD(i1)];
            float2 wv = cmul(w, v);
            data[PAD(i0)] = make_float2(u.x + wv.x, u.y + wv.y);
            data[PAD(i1)] = make_float2(u.x - wv.x, u.y - wv.y);
        }
        __syncthreads();

        // real-split postprocess -> S[0..2048]
        float2* So = (float2*)(S + (size_t)ch * NBINS * 2);
        for (int k = tid; k < NBINS; k += 512) {
            float2 Zk = data[PAD(k & (NH - 1))];
            float2 Zm = data[PAD((NH - k) & (NH - 1))];
            float er = 0.5f * (Zk.x + Zm.x);
            float ei = 0.5f * (Zk.y - Zm.y);
            float dr = Zk.x - Zm.x;
            float di = Zk.y + Zm.y;
            float orr = 0.5f * di;
            float oii = -0.5f * dr;
            float2 W;
            if (k == 2048) {
                W = make_float2(-1.0f, 0.0f);
            } else {
                float2 t = tw[k >> 1];
                if (k & 1) W = make_float2(t.x * CQ + t.y * SQ,
                                           t.y * CQ - t.x * SQ);
                else       W = t;
            }
            So[k] = make_float2(er + W.x * orr - W.y * oii,
                                ei + W.x * oii + W.y * orr);
        }
        __syncthreads();   // protect data[] before any next iteration
    }
    gg.sync();

    // ------------------- Phase 2: PHAT + lag DFT -> cc --------------------
    float2* phs = data;              // alias (2049 <= 2175)
    int BP = B * P;
    for (int u = bid; u < BP; u += nb) {
        int b = u / P, p = u - b * P;
        int ma = comb[p * 2 + 0];
        int mb = comb[p * 2 + 1];
        const float2* Sa = (const float2*)(S + ((size_t)(b * 8 + ma)) * NBINS * 2);
        const float2* Sb = (const float2*)(S + ((size_t)(b * 8 + mb)) * NBINS * 2);

        __syncthreads();             // LDS reuse guard
        for (int k = tid; k < NBINS; k += 512) {
            float2 a = Sa[k];
            float2 c = Sb[k];
            float Xr = a.x * c.x + a.y * c.y;     // Sa * conj(Sb)
            float Xi = a.y * c.x - a.x * c.y;
            float mag = sqrtf(Xr * Xr + Xi * Xi);
            float w = (k == 0 || k == NH) ? 1.0f : 2.0f;
            float inv = w / (mag + 1e-12f);
            phs[k] = make_float2(Xr * inv, Xi * inv);
        }
        __syncthreads();

        if (tid < 41 * NCHK) {
            int n = tid / NCHK;                   // |lag| 0..40
            int c = tid - n * NCHK;               // chunk 0..11
            int kk0 = c * CHLEN;
            int kk1 = kk0 + CHLEN;
            if (kk1 > NBINS) kk1 = NBINS;

            float step = (2.0f * PI_F / (float)N_FFT) * (float)n;
            float sv, cv;
            sincosf(step, &sv, &cv);
            float wr = cv, wi = sv;               // e^{+i step}
            sincosf(step * (float)kk0, &sv, &cv);
            float rr = cv, ri = sv;               // e^{+i step kk0}

            float Cr = 0.0f, Ci = 0.0f;
            for (int k = kk0; k < kk1; ++k) {
                float2 ph = phs[k];
                Cr = fmaf(ph.x, rr, Cr);
                Ci = fmaf(ph.y, ri, Ci);
                float nr = rr * wr - ri * wi;
                float ni = rr * wi + ri * wr;
                rr = nr; ri = ni;
            }
            partCr[tid] = Cr;
            partCi[tid] = Ci;
        }
        __syncthreads();

        if (tid < 41) {
            float Cr = 0.0f, Ci = 0.0f;
            #pragma unroll
            for (int c = 0; c < NCHK; ++c) {
                Cr += partCr[tid * NCHK + c];
                Ci += partCi[tid * NCHK + c];
            }
            float* outp = cc + (size_t)u * NLAGS;     // exclusive owner: no atomics
            outp[MAXTAU + tid] = Cr - Ci;
            if (tid > 0) outp[MAXTAU - tid] = Cr + Ci;
        }
    }
    gg.sync();

    // ------------------- Phase 3: power + argmax --------------------------
    float* ccs = (float*)data;       // alias (2268 floats <= 4350)
    const float scale = 1.0f / (float)N_FFT;
    int NU = B * nchunks;
    for (int u = bid; u < NU; u += nb) {
        int b     = u % B;           // b fastest: 16 units share one tau chunk in L2
        int chunk = u / B;

        __syncthreads();             // LDS reuse guard
        const float4* csrc = (const float4*)(cc + (size_t)b * P * NLAGS);
        float4* cdst = (float4*)ccs;
        for (int i = tid; i < (P * NLAGS) / 4; i += 512) {   // 567 float4
            float4 v4 = csrc[i];
            cdst[i] = make_float4(v4.x * scale, v4.y * scale, v4.z * scale, v4.w * scale);
        }
        __syncthreads();

        int g = chunk * 512 + tid;
        float v = -1e30f;
        int   gi = 0x7fffffff;
        if (g < G) {
            const int4* tp = (const int4*)(tau + (size_t)g * 28);
            v = 0.0f;
            #pragma unroll
            for (int q = 0; q < 7; ++q) {
                int4 tv = tp[q];
                v += ccs[(q * 4 + 0) * NLAGS + tv.x];
                v += ccs[(q * 4 + 1) * NLAGS + tv.y];
                v += ccs[(q * 4 + 2) * NLAGS + tv.z];
                v += ccs[(q * 4 + 3) * NLAGS + tv.w];
            }
            gi = g;
        }

        #pragma unroll
        for (int off = 32; off > 0; off >>= 1) {
            float v2 = __shfl_down(v, off);
            int   i2 = __shfl_down(gi, off);
            if (v2 > v || (v2 == v && i2 < gi)) { v = v2; gi = i2; }
        }
        int lane = tid & 63, wv = tid >> 6;
        if (lane == 0) { wval[wv] = v; widx[wv] = gi; }
        __syncthreads();
        if (tid == 0) {
            #pragma unroll
            for (int w = 1; w < 8; ++w) {
                float v2 = wval[w]; int i2 = widx[w];
                if (v2 > v || (v2 == v && i2 < gi)) { v = v2; gi = i2; }
            }
            // monotonic float->uint; pack value hi, ~index lo (ties -> lowest idx)
            unsigned vb = __float_as_uint(v);
            vb = (vb & 0x80000000u) ? ~vb : (vb | 0x80000000u);
            unsigned long long key = ((unsigned long long)vb << 32)
                                   | (unsigned long long)(0xFFFFFFFFu - (unsigned)gi);
            atomicMax(packed + b, key);
        }
    }
    gg.sync();

    // ------------------- Phase 4: write outputs ---------------------------
    if (bid < B && tid == 0) {
        unsigned long long k = packed[bid];
        int gi = (int)(0xFFFFFFFFu - (unsigned)(k & 0xFFFFFFFFull));
        out[bid * 3 + 0] = grid_x[(size_t)gi * 3 + 0] - rec_centroid[0];
        out[bid * 3 + 1] = grid_x[(size_t)gi * 3 + 1] - rec_centroid[1];
        out[bid * 3 + 2] = grid_x[(size_t)gi * 3 + 2] - rec_centroid[2];
    }
}

// ===========================================================================
// FALLBACK PATH: the proven 4-kernel pipeline (verbatim from the 93.6 us
// version), used only if hipLaunchCooperativeKernel returns a synchronous
// error (e.g. cooperative launch not capturable).
// ===========================================================================
__global__ __launch_bounds__(512)
void rfft_kernel(const float* __restrict__ sig,
                 float* __restrict__ S,
                 float* __restrict__ cc, int ccN) {
    int bm  = (int)blockIdx.x;
    int tid = (int)threadIdx.x;

    __shared__ float2 data[PAD(NH - 1) + 1];
    __shared__ float2 tw[NH / 2];

    for (int i = bm * 512 + tid; i < ccN; i += (int)gridDim.x * 512)
        cc[i] = 0.0f;

    for (int j = tid; j < NH / 2; j += 512) {
        float sv, cv;
        sincosf(-(2.0f * PI_F / (float)NH) * (float)j, &sv, &cv);
        tw[j] = make_float2(cv, sv);
    }

    const float2* sp = (const float2*)(sig + (size_t)bm * N_FFT);
    for (int i = tid; i < NH; i += 512) {
        float2 v = sp[i];
        int j = (int)(__brev((unsigned)i) >> 21);
        data[PAD(j)] = v;
    }
    __syncthreads();

    for (int s = 1; s <= 9; s += 2) {
        int h  = 1 << (s - 1);
        int j  = tid & (h - 1);
        int g  = tid >> (s - 1);
        int i0 = (g << (s + 1)) + j;
        int i1 = i0 + h, i2 = i0 + 2 * h, i3 = i0 + 3 * h;

        float2 w1 = tw[j << (11 - s)];
        float2 wA = tw[j << (10 - s)];
        float2 wB = tw[(j + h) << (10 - s)];

        float2 a = data[PAD(i0)];
        float2 b = data[PAD(i1)];
        float2 c = data[PAD(i2)];
        float2 d = data[PAD(i3)];

        float2 wb = cmul(w1, b), wd = cmul(w1, d);
        float2 a1 = make_float2(a.x + wb.x, a.y + wb.y);
        float2 b1 = make_float2(a.x - wb.x, a.y - wb.y);
        float2 c1 = make_float2(c.x + wd.x, c.y + wd.y);
        float2 d1 = make_float2(c.x - wd.x, c.y - wd.y);
        float2 wc = cmul(wA, c1), wdd = cmul(wB, d1);
        data[PAD(i0)] = make_float2(a1.x + wc.x,  a1.y + wc.y);
        data[PAD(i2)] = make_float2(a1.x - wc.x,  a1.y - wc.y);
        data[PAD(i1)] = make_float2(b1.x + wdd.x, b1.y + wdd.y);
        data[PAD(i3)] = make_float2(b1.x - wdd.x, b1.y - wdd.y);
        __syncthreads();
    }

    for (int t = tid; t < 1024; t += 512) {
        int i0 = t, i1 = t + 1024;
        float2 w = tw[t];
        float2 u = data[PAD(i0)];
        float2 v = data[PAD(i1)];
        float2 wv = cmul(w, v);
        data[PAD(i0)] = make_float2(u.x + wv.x, u.y + wv.y);
        data[PAD(i1)] = make_float2(u.x - wv.x, u.y - wv.y);
    }
    __syncthreads();

    float2* So = (float2*)(S + (size_t)bm * NBINS * 2);
    for (int k = tid; k < NBINS; k += 512) {
        float2 Zk = data[PAD(k & (NH - 1))];
        float2 Zm = data[PAD((NH - k) & (NH - 1))];
        float er = 0.5f * (Zk.x + Zm.x);
        float ei = 0.5f * (Zk.y - Zm.y);
        float dr = Zk.x - Zm.x;
        float di = Zk.y + Zm.y;
        float orr = 0.5f * di;
        float oii = -0.5f * dr;
        float2 W;
        if (k == 2048) {
            W = make_float2(-1.0f, 0.0f);
        } else {
            float2 t = tw[k >> 1];
            if (k & 1) W = make_float2(t.x * CQ + t.y * SQ,
                                       t.y * CQ - t.x * SQ);
            else       W = t;
        }
        So[k] = make_float2(er + W.x * orr - W.y * oii,
                            ei + W.x * oii + W.y * orr);
    }
}

#define NCH 6
#define CHLEN_F 43
__global__ __launch_bounds__(256)
void phat_cc_kernel(const float* __restrict__ S,
                    const int* __restrict__ comb,
                    float* __restrict__ cc, int P) {
    int id  = (int)blockIdx.x;
    int seg = id & (NSEG - 1);
    int bp  = id >> 3;
    int b   = bp / P;
    int p   = bp % P;
    int ma = comb[p * 2 + 0];
    int mb = comb[p * 2 + 1];
    const float2* Sa = (const float2*)(S + ((size_t)(b * 8 + ma)) * NBINS * 2);
    const float2* Sb = (const float2*)(S + ((size_t)(b * 8 + mb)) * NBINS * 2);

    int k0 = seg * SEGLEN;
    int k1 = (seg == NSEG - 1) ? NBINS : (k0 + SEGLEN);

    __shared__ float2 phs[SEGLEN + 1];
    __shared__ float partCr[41 * NCH];
    __shared__ float partCi[41 * NCH];

    int tid = (int)threadIdx.x;
    for (int k = k0 + tid; k < k1; k += 256) {
        float2 a = Sa[k];
        float2 c = Sb[k];
        float Xr = a.x * c.x + a.y * c.y;
        float Xi = a.y * c.x - a.x * c.y;
        float mag = sqrtf(Xr * Xr + Xi * Xi);
        float w = (k == 0 || k == 2048) ? 1.0f : 2.0f;
        float inv = w / (mag + 1e-12f);
        phs[k - k0] = make_float2(Xr * inv, Xi * inv);
    }
    __syncthreads();

    if (tid < 41 * NCH) {
        int n = tid % 41;
        int c = tid / 41;
        int kk0 = k0 + c * CHLEN_F;
        int kk1 = kk0 + CHLEN_F;
        if (kk1 > k1) kk1 = k1;

        float step = (2.0f * PI_F / (float)N_FFT) * (float)n;
        float sv, cv;
        sincosf(step, &sv, &cv);
        float wr = cv, wi = sv;
        sincosf(step * (float)kk0, &sv, &cv);
        float rr = cv, ri = sv;

        float Cr = 0.0f, Ci = 0.0f;
        for (int k = kk0; k < kk1; ++k) {
            float2 ph = phs[k - k0];
            Cr = fmaf(ph.x, rr, Cr);
            Ci = fmaf(ph.y, ri, Ci);
            float nr = rr * wr - ri * wi;
            float ni = rr * wi + ri * wr;
            rr = nr; ri = ni;
        }
        partCr[tid] = Cr;
        partCi[tid] = Ci;
    }
    __syncthreads();

    if (tid < 41) {
        float Cr = 0.0f, Ci = 0.0f;
        #pragma unroll
        for (int c = 0; c < NCH; ++c) {
            Cr += partCr[tid + 41 * c];
            Ci += partCi[tid + 41 * c];
        }
        float* outp = cc + (size_t)bp * NLAGS;
        atomicAdd(&outp[MAXTAU + tid], Cr - Ci);
        if (tid > 0) atomicAdd(&outp[MAXTAU - tid], Cr + Ci);
    }
}

__global__ __launch_bounds__(512)
void power_argmax_kernel(const float* __restrict__ cc,
                         const int* __restrict__ tau,
                         int G, int P,
                         float* __restrict__ pval,
                         int* __restrict__ pidx, int nchunks) {
    int b     = (int)blockIdx.y;
    int chunk = (int)blockIdx.x;
    int tid   = (int)threadIdx.x;

    __shared__ float ccs[28 * NLAGS];
    const float4* csrc = (const float4*)(cc + (size_t)b * P * NLAGS);
    float4* cdst = (float4*)ccs;
    const float scale = 1.0f / (float)N_FFT;
    for (int i = tid; i < 28 * NLAGS / 4; i += 512) {
        float4 v = csrc[i];
        cdst[i] = make_float4(v.x * scale, v.y * scale, v.z * scale, v.w * scale);
    }
    __syncthreads();

    int g = chunk * 512 + tid;
    float v = -1e30f;
    int   gi = 0x7fffffff;
    if (g < G) {
        const int4* tp = (const int4*)(tau + (size_t)g * 28);
        v = 0.0f;
        #pragma unroll
        for (int q = 0; q < 7; ++q) {
            int4 tv = tp[q];
            v += ccs[(q * 4 + 0) * NLAGS + tv.x];
            v += ccs[(q * 4 + 1) * NLAGS + tv.y];
            v += ccs[(q * 4 + 2) * NLAGS + tv.z];
            v += ccs[(q * 4 + 3) * NLAGS + tv.w];
        }
        gi = g;
    }

    #pragma unroll
    for (int off = 32; off > 0; off >>= 1) {
        float v2 = __shfl_down(v, off);
        int   i2 = __shfl_down(gi, off);
        if (v2 > v || (v2 == v && i2 < gi)) { v = v2; gi = i2; }
    }
    __shared__ float wval[8];
    __shared__ int   widx[8];
    int lane = tid & 63, wv = tid >> 6;
    if (lane == 0) { wval[wv] = v; widx[wv] = gi; }
    __syncthreads();
    if (tid == 0) {
        #pragma unroll
        for (int w = 1; w < 8; ++w) {
            float v2 = wval[w]; int i2 = widx[w];
            if (v2 > v || (v2 == v && i2 < gi)) { v = v2; gi = i2; }
        }
        pval[b * nchunks + chunk] = v;
        pidx[b * nchunks + chunk] = gi;
    }
}

__global__ void finalize_kernel(const float* __restrict__ pval,
                                const int* __restrict__ pidx, int nchunks,
                                const float* __restrict__ grid_x,
                                const float* __restrict__ rec_centroid,
                                float* __restrict__ out) {
    int b = (int)blockIdx.x;
    int l = (int)threadIdx.x;
    float v = -1e30f; int gi = 0x7fffffff;
    for (int j = l; j < nchunks; j += 64) {
        float v2 = pval[b * nchunks + j];
        int   i2 = pidx[b * nchunks + j];
        if (v2 > v || (v2 == v && i2 < gi)) { v = v2; gi = i2; }
    }
    #pragma unroll
    for (int off = 32; off > 0; off >>= 1) {
        float v2 = __shfl_down(v, off);
        int   i2 = __shfl_down(gi, off);
        if (v2 > v || (v2 == v && i2 < gi)) { v = v2; gi = i2; }
    }
    if (l == 0) {
        for (int c = 0; c < 3; ++c)
            out[b * 3 + c] = grid_x[(size_t)gi * 3 + c] - rec_centroid[c];
    }
}

extern "C" void kernel_launch(void* const* d_in, const int* in_sizes, int n_in,
                              void* d_out, int out_size, void* d_ws, size_t ws_size,
                              hipStream_t stream) {
    const float* signal       = (const float*)d_in[0];
    const float* grid_x       = (const float*)d_in[1];
    const int*   tau          = (const int*)d_in[2];
    const int*   comb         = (const int*)d_in[3];
    const float* rec_centroid = (const float*)d_in[4];
    float* out = (float*)d_out;

    int G  = in_sizes[1] / 3;          // ~31416 grid points
    int P  = in_sizes[3] / 2;          // 28 pairs
    int BM = in_sizes[0] / N_FFT;      // 128 channels
    int B  = BM / 8;                   // 16 batches
    int BP = B * P;                    // 448
    int nchunks = (G + 511) / 512;

    // workspace layout (16B-aligned: all offsets multiples of 16)
    float* S  = (float*)d_ws;                          // BM*2049*2 floats
    float* cc = S + (size_t)BM * NBINS * 2;            // BP*81 floats (145,152 B)
    unsigned long long* packed = (unsigned long long*)(cc + (size_t)BP * NLAGS); // B u64
    float* pval = (float*)(packed + 16);               // fallback only
    int*   pidx = (int*)(pval + (size_t)B * nchunks);

    void* kargs[] = {
        (void*)&signal, (void*)&comb, (void*)&tau, (void*)&grid_x,
        (void*)&rec_centroid, (void*)&out, (void*)&S, (void*)&cc,
        (void*)&packed, (void*)&BM, (void*)&P, (void*)&B, (void*)&G,
        (void*)&nchunks
    };
    hipError_t err = hipLaunchCooperativeKernel((const void*)mega_kernel,
                                                dim3(NBLOCKS), dim3(512),
                                                kargs, 0, stream);
    if (err != hipSuccess) {
        // fallback: proven 4-kernel pipeline
        (void)hipGetLastError();
        rfft_kernel<<<BM, 512, 0, stream>>>(signal, S, cc, BP * NLAGS);
        phat_cc_kernel<<<BP * NSEG, 256, 0, stream>>>(S, comb, cc, P);
        power_argmax_kernel<<<dim3(nchunks, B), 512, 0, stream>>>(cc, tau, G, P, pval, pidx, nchunks);
        finalize_kernel<<<B, 64, 0, stream>>>(pval, pidx, nchunks, grid_x, rec_centroid, out);
    }
}

// Round 2
// 107.067 us; speedup vs baseline: 1.8299x; 1.8299x over previous
//
#include <hip/hip_runtime.h>

#define N_FFT 4096
#define NH    2048          // N_FFT/2 (complex FFT length)
#define NBINS 2049          // N_FFT/2 + 1
#define NLAGS 81            // 2*MAX_TAU + 1
#define MAXTAU 40
#define NSEG  8             // k-segments per (b,p) pair
#define SEGLEN 256
#define PI_F 3.14159265358979323846f
#define PAD(i) ((i) + ((i) >> 4))   // LDS bank-conflict padding (+1 per 16)

// e^{-2*pi*i/4096} as f32 constants (cos, sin)
#define CQ 0.99999882345f
#define SQ 0.00153398019f

__device__ __forceinline__ float2 cmul(float2 a, float2 b) {
    return make_float2(a.x * b.x - a.y * b.y, a.x * b.y + a.y * b.x);
}

// ---------------------------------------------------------------------------
// Kernel 1: rfft per (b,m) channel, fp32, packed-complex FFT in LDS.
// Two radix-2 stages per barrier (radix-4 dataflow). Postprocess twiddles via
// parity trick; S written as vectorized float2. Zeroes cc + packed + cnt for
// the downstream atomics (stream order guarantees completion before use).
// ---------------------------------------------------------------------------
__global__ __launch_bounds__(512)
void rfft_kernel(const float* __restrict__ sig,
                 float* __restrict__ S,
                 float* __restrict__ zero_region, int zeroN) {
    int bm  = (int)blockIdx.x;
    int tid = (int)threadIdx.x;

    __shared__ float2 data[PAD(NH - 1) + 1];   // 2175 float2 = 17.4 KB
    __shared__ float2 tw[NH / 2];              //  8 KB

    // zero cc (atomic accumulation) + packed keys + counters (fused finalize)
    for (int i = bm * 512 + tid; i < zeroN; i += (int)gridDim.x * 512)
        zero_region[i] = 0.0f;

    // twiddle table
    for (int j = tid; j < NH / 2; j += 512) {
        float sv, cv;
        sincosf(-(2.0f * PI_F / (float)NH) * (float)j, &sv, &cv);
        tw[j] = make_float2(cv, sv);
    }

    // load packed real pairs, scatter to bit-reversed position
    const float2* sp = (const float2*)(sig + (size_t)bm * N_FFT);
    for (int i = tid; i < NH; i += 512) {
        float2 v = sp[i];
        int j = (int)(__brev((unsigned)i) >> 21);   // 11-bit reverse
        data[PAD(j)] = v;
    }
    __syncthreads();

    // stages 1..10 as 5 combined passes (two radix-2 levels per barrier)
    for (int s = 1; s <= 9; s += 2) {
        int h  = 1 << (s - 1);
        int j  = tid & (h - 1);
        int g  = tid >> (s - 1);
        int i0 = (g << (s + 1)) + j;
        int i1 = i0 + h, i2 = i0 + 2 * h, i3 = i0 + 3 * h;

        float2 w1 = tw[j << (11 - s)];
        float2 wA = tw[j << (10 - s)];
        float2 wB = tw[(j + h) << (10 - s)];

        float2 a = data[PAD(i0)];
        float2 b = data[PAD(i1)];
        float2 c = data[PAD(i2)];
        float2 d = data[PAD(i3)];

        // stage s
        float2 wb = cmul(w1, b), wd = cmul(w1, d);
        float2 a1 = make_float2(a.x + wb.x, a.y + wb.y);
        float2 b1 = make_float2(a.x - wb.x, a.y - wb.y);
        float2 c1 = make_float2(c.x + wd.x, c.y + wd.y);
        float2 d1 = make_float2(c.x - wd.x, c.y - wd.y);
        // stage s+1
        float2 wc = cmul(wA, c1), wdd = cmul(wB, d1);
        data[PAD(i0)] = make_float2(a1.x + wc.x,  a1.y + wc.y);
        data[PAD(i2)] = make_float2(a1.x - wc.x,  a1.y - wc.y);
        data[PAD(i1)] = make_float2(b1.x + wdd.x, b1.y + wdd.y);
        data[PAD(i3)] = make_float2(b1.x - wdd.x, b1.y - wdd.y);
        __syncthreads();
    }

    // stage 11 (half = 1024): 1024 butterflies, 2 per thread
    for (int t = tid; t < 1024; t += 512) {
        int i0 = t, i1 = t + 1024;
        float2 w = tw[t];
        float2 u = data[PAD(i0)];
        float2 v = data[PAD(i1)];
        float2 wv = cmul(w, v);
        data[PAD(i0)] = make_float2(u.x + wv.x, u.y + wv.y);
        data[PAD(i1)] = make_float2(u.x - wv.x, u.y - wv.y);
    }
    __syncthreads();

    // real-split postprocess -> X[0..2048], parity-trick twiddle, float2 store
    float2* So = (float2*)(S + (size_t)bm * NBINS * 2);
    for (int k = tid; k < NBINS; k += 512) {
        float2 Zk = data[PAD(k & (NH - 1))];
        float2 Zm = data[PAD((NH - k) & (NH - 1))];
        float er = 0.5f * (Zk.x + Zm.x);
        float ei = 0.5f * (Zk.y - Zm.y);
        float dr = Zk.x - Zm.x;
        float di = Zk.y + Zm.y;
        float orr = 0.5f * di;       // O = -i*d/2
        float oii = -0.5f * dr;
        float2 W;
        if (k == 2048) {
            W = make_float2(-1.0f, 0.0f);
        } else {
            float2 t = tw[k >> 1];
            if (k & 1) W = make_float2(t.x * CQ + t.y * SQ,
                                       t.y * CQ - t.x * SQ);
            else       W = t;
        }
        So[k] = make_float2(er + W.x * orr - W.y * oii,
                            ei + W.x * oii + W.y * orr);
    }
}

// ---------------------------------------------------------------------------
// Kernel 2: per (b,p,seg): PHAT (irfft weight folded) for 256(+1) bins into
// LDS, then lag partials via n/-n symmetry; fp32 atomicAdd into cc.
// (Unchanged from the proven 93.6 us version.)
// ---------------------------------------------------------------------------
#define NCH 6
#define CHLEN 43
__global__ __launch_bounds__(256)
void phat_cc_kernel(const float* __restrict__ S,
                    const int* __restrict__ comb,
                    float* __restrict__ cc, int P) {
    int id  = (int)blockIdx.x;
    int seg = id & (NSEG - 1);
    int bp  = id >> 3;
    int b   = bp / P;
    int p   = bp % P;
    int ma = comb[p * 2 + 0];
    int mb = comb[p * 2 + 1];
    const float2* Sa = (const float2*)(S + ((size_t)(b * 8 + ma)) * NBINS * 2);
    const float2* Sb = (const float2*)(S + ((size_t)(b * 8 + mb)) * NBINS * 2);

    int k0 = seg * SEGLEN;
    int k1 = (seg == NSEG - 1) ? NBINS : (k0 + SEGLEN);   // last seg: 257 bins

    __shared__ float2 phs[SEGLEN + 1];       // 2,056 B
    __shared__ float partCr[41 * NCH];       //   984 B
    __shared__ float partCi[41 * NCH];

    int tid = (int)threadIdx.x;
    for (int k = k0 + tid; k < k1; k += 256) {
        float2 a = Sa[k];
        float2 c = Sb[k];
        float Xr = a.x * c.x + a.y * c.y;     // Sa * conj(Sb)
        float Xi = a.y * c.x - a.x * c.y;
        float mag = sqrtf(Xr * Xr + Xi * Xi);
        float w = (k == 0 || k == 2048) ? 1.0f : 2.0f;
        float inv = w / (mag + 1e-12f);
        phs[k - k0] = make_float2(Xr * inv, Xi * inv);
    }
    __syncthreads();

    if (tid < 41 * NCH) {
        int n = tid % 41;                      // |lag| 0..40
        int c = tid / 41;
        int kk0 = k0 + c * CHLEN;
        int kk1 = kk0 + CHLEN;
        if (kk1 > k1) kk1 = k1;

        float step = (2.0f * PI_F / (float)N_FFT) * (float)n;
        float sv, cv;
        sincosf(step, &sv, &cv);
        float wr = cv, wi = sv;               // e^{+i step}
        sincosf(step * (float)kk0, &sv, &cv);
        float rr = cv, ri = sv;               // e^{+i step kk0}

        float Cr = 0.0f, Ci = 0.0f;
        for (int k = kk0; k < kk1; ++k) {
            float2 ph = phs[k - k0];
            Cr = fmaf(ph.x, rr, Cr);
            Ci = fmaf(ph.y, ri, Ci);
            float nr = rr * wr - ri * wi;
            float ni = rr * wi + ri * wr;
            rr = nr; ri = ni;
        }
        partCr[tid] = Cr;
        partCi[tid] = Ci;
    }
    __syncthreads();

    if (tid < 41) {
        float Cr = 0.0f, Ci = 0.0f;
        #pragma unroll
        for (int c = 0; c < NCH; ++c) {
            Cr += partCr[tid + 41 * c];
            Ci += partCi[tid + 41 * c];
        }
        float* outp = cc + (size_t)bp * NLAGS;
        atomicAdd(&outp[MAXTAU + tid], Cr - Ci);
        if (tid > 0) atomicAdd(&outp[MAXTAU - tid], Cr + Ci);
    }
}

// ---------------------------------------------------------------------------
// Kernel 3: power + argmax + FUSED finalize.
// Per-block result published as a packed u64 key (monotonic-float value in
// the high word, ~index in the low word: ties -> lowest index, matching
// np.argmax) via device-scope atomicMax — this exact packing was
// correctness-verified in the round-1 cooperative kernel. The last block per
// batch (atomic counter, zeroed by kernel 1 two dispatches earlier) atomically
// reads the final key and writes the output. All cross-block communication is
// atomics-only: no plain-store publication, no spinning, no residency
// assumptions.
// ---------------------------------------------------------------------------
__global__ __launch_bounds__(512)
void power_argmax_kernel(const float* __restrict__ cc,
                         const int* __restrict__ tau,
                         int G, int P,
                         unsigned long long* __restrict__ packed,
                         int* __restrict__ cnt,
                         const float* __restrict__ grid_x,
                         const float* __restrict__ rec_centroid,
                         float* __restrict__ out, int nchunks) {
    int b     = (int)blockIdx.y;
    int chunk = (int)blockIdx.x;
    int tid   = (int)threadIdx.x;

    __shared__ float ccs[28 * NLAGS];   // 9,072 B (2268 floats = 567 float4)
    const float4* csrc = (const float4*)(cc + (size_t)b * P * NLAGS);
    float4* cdst = (float4*)ccs;
    const float scale = 1.0f / (float)N_FFT;
    for (int i = tid; i < 28 * NLAGS / 4; i += 512) {
        float4 v = csrc[i];
        cdst[i] = make_float4(v.x * scale, v.y * scale, v.z * scale, v.w * scale);
    }
    __syncthreads();

    int g = chunk * 512 + tid;
    float v = -1e30f;
    int   gi = 0x7fffffff;
    if (g < G) {
        const int4* tp = (const int4*)(tau + (size_t)g * 28);
        v = 0.0f;
        #pragma unroll
        for (int q = 0; q < 7; ++q) {
            int4 tv = tp[q];
            v += ccs[(q * 4 + 0) * NLAGS + tv.x];
            v += ccs[(q * 4 + 1) * NLAGS + tv.y];
            v += ccs[(q * 4 + 2) * NLAGS + tv.z];
            v += ccs[(q * 4 + 3) * NLAGS + tv.w];
        }
        gi = g;
    }

    #pragma unroll
    for (int off = 32; off > 0; off >>= 1) {
        float v2 = __shfl_down(v, off);
        int   i2 = __shfl_down(gi, off);
        if (v2 > v || (v2 == v && i2 < gi)) { v = v2; gi = i2; }
    }
    __shared__ float wval[8];
    __shared__ int   widx[8];
    int lane = tid & 63, wv = tid >> 6;
    if (lane == 0) { wval[wv] = v; widx[wv] = gi; }
    __syncthreads();
    if (tid == 0) {
        #pragma unroll
        for (int w = 1; w < 8; ++w) {
            float v2 = wval[w]; int i2 = widx[w];
            if (v2 > v || (v2 == v && i2 < gi)) { v = v2; gi = i2; }
        }
        // monotonic float->uint; pack value hi, ~index lo (ties -> lowest idx)
        unsigned vb = __float_as_uint(v);
        vb = (vb & 0x80000000u) ? ~vb : (vb | 0x80000000u);
        unsigned long long key = ((unsigned long long)vb << 32)
                               | (unsigned long long)(0xFFFFFFFFu - (unsigned)gi);
        atomicMax(packed + b, key);
        __threadfence();   // order the atomicMax before the counter bump
        int old = atomicAdd(cnt + b, 1);
        if (old == nchunks - 1) {
            // last block for this batch: all 62 keys are at the coherent
            // point; atomic read returns the global max.
            unsigned long long k = atomicAdd(packed + b, 0ull);
            int win = (int)(0xFFFFFFFFu - (unsigned)(k & 0xFFFFFFFFull));
            out[b * 3 + 0] = grid_x[(size_t)win * 3 + 0] - rec_centroid[0];
            out[b * 3 + 1] = grid_x[(size_t)win * 3 + 1] - rec_centroid[1];
            out[b * 3 + 2] = grid_x[(size_t)win * 3 + 2] - rec_centroid[2];
        }
    }
}

extern "C" void kernel_launch(void* const* d_in, const int* in_sizes, int n_in,
                              void* d_out, int out_size, void* d_ws, size_t ws_size,
                              hipStream_t stream) {
    const float* signal       = (const float*)d_in[0];
    const float* grid_x       = (const float*)d_in[1];
    const int*   tau          = (const int*)d_in[2];
    const int*   comb         = (const int*)d_in[3];
    const float* rec_centroid = (const float*)d_in[4];
    float* out = (float*)d_out;

    int G  = in_sizes[1] / 3;          // ~31416 grid points
    int P  = in_sizes[3] / 2;          // 28 pairs
    int BM = in_sizes[0] / N_FFT;      // 128 channels
    int B  = BM / 8;                   // 16 batches
    int BP = B * P;                    // 448
    int nchunks = (G + 511) / 512;

    // workspace layout (16B-aligned throughout: offsets are multiples of 16)
    float* S  = (float*)d_ws;                      // BM*2049*2 floats (2.1 MB)
    float* cc = S + (size_t)BM * NBINS * 2;        // BP*81 floats (145,152 B)
    unsigned long long* packed =
        (unsigned long long*)(cc + (size_t)BP * NLAGS);   // B u64 (128 B)
    int* cnt = (int*)(packed + B);                 // B ints

    // kernel 1 zeroes cc + packed + cnt in one contiguous pass:
    // BP*NLAGS floats + B u64 (2 floats each) + B ints (1 float each)
    int zeroN = BP * NLAGS + B * 2 + B;

    rfft_kernel<<<BM, 512, 0, stream>>>(signal, S, cc, zeroN);
    phat_cc_kernel<<<BP * NSEG, 256, 0, stream>>>(S, comb, cc, P);
    power_argmax_kernel<<<dim3(nchunks, B), 512, 0, stream>>>(
        cc, tau, G, P, packed, cnt, grid_x, rec_centroid, out, nchunks);
}

// Round 3
// 95.495 us; speedup vs baseline: 2.0516x; 1.1212x over previous
//
#include <hip/hip_runtime.h>

#define N_FFT 4096
#define NH    2048          // N_FFT/2 (complex FFT length)
#define NBINS 2049          // N_FFT/2 + 1
#define NLAGS 81            // 2*MAX_TAU + 1
#define MAXTAU 40
#define NSEG  8             // k-segments per (b,p) pair
#define SEGLEN 256
#define PI_F 3.14159265358979323846f
#define PAD(i) ((i) + ((i) >> 4))   // LDS bank-conflict padding (+1 per 16)

// e^{-2*pi*i/4096} as f32 constants (cos, sin)
#define CQ 0.99999882345f
#define SQ 0.00153398019f

__device__ __forceinline__ float2 cmul(float2 a, float2 b) {
    return make_float2(a.x * b.x - a.y * b.y, a.x * b.y + a.y * b.x);
}

// ---------------------------------------------------------------------------
// Kernel 1: rfft per (b,m) channel, fp32, packed-complex FFT in LDS.
// Two radix-2 stages per barrier (radix-4 dataflow). Postprocess twiddles via
// parity trick; S written as vectorized float2. Zeroes cc for phat atomics.
// ---------------------------------------------------------------------------
__global__ __launch_bounds__(512)
void rfft_kernel(const float* __restrict__ sig,
                 float* __restrict__ S,
                 float* __restrict__ cc, int ccN) {
    int bm  = (int)blockIdx.x;
    int tid = (int)threadIdx.x;

    __shared__ float2 data[PAD(NH - 1) + 1];   // 2175 float2 = 17.4 KB
    __shared__ float2 tw[NH / 2];              //  8 KB

    // zero cc for the atomic accumulation downstream
    for (int i = bm * 512 + tid; i < ccN; i += (int)gridDim.x * 512)
        cc[i] = 0.0f;

    // twiddle table
    for (int j = tid; j < NH / 2; j += 512) {
        float sv, cv;
        sincosf(-(2.0f * PI_F / (float)NH) * (float)j, &sv, &cv);
        tw[j] = make_float2(cv, sv);
    }

    // load packed real pairs, scatter to bit-reversed position
    const float2* sp = (const float2*)(sig + (size_t)bm * N_FFT);
    for (int i = tid; i < NH; i += 512) {
        float2 v = sp[i];
        int j = (int)(__brev((unsigned)i) >> 21);   // 11-bit reverse
        data[PAD(j)] = v;
    }
    __syncthreads();

    // stages 1..10 as 5 combined passes (two radix-2 levels per barrier)
    for (int s = 1; s <= 9; s += 2) {
        int h  = 1 << (s - 1);
        int j  = tid & (h - 1);
        int g  = tid >> (s - 1);
        int i0 = (g << (s + 1)) + j;
        int i1 = i0 + h, i2 = i0 + 2 * h, i3 = i0 + 3 * h;

        float2 w1 = tw[j << (11 - s)];
        float2 wA = tw[j << (10 - s)];
        float2 wB = tw[(j + h) << (10 - s)];

        float2 a = data[PAD(i0)];
        float2 b = data[PAD(i1)];
        float2 c = data[PAD(i2)];
        float2 d = data[PAD(i3)];

        // stage s
        float2 wb = cmul(w1, b), wd = cmul(w1, d);
        float2 a1 = make_float2(a.x + wb.x, a.y + wb.y);
        float2 b1 = make_float2(a.x - wb.x, a.y - wb.y);
        float2 c1 = make_float2(c.x + wd.x, c.y + wd.y);
        float2 d1 = make_float2(c.x - wd.x, c.y - wd.y);
        // stage s+1
        float2 wc = cmul(wA, c1), wdd = cmul(wB, d1);
        data[PAD(i0)] = make_float2(a1.x + wc.x,  a1.y + wc.y);
        data[PAD(i2)] = make_float2(a1.x - wc.x,  a1.y - wc.y);
        data[PAD(i1)] = make_float2(b1.x + wdd.x, b1.y + wdd.y);
        data[PAD(i3)] = make_float2(b1.x - wdd.x, b1.y - wdd.y);
        __syncthreads();
    }

    // stage 11 (half = 1024): 1024 butterflies, 2 per thread
    for (int t = tid; t < 1024; t += 512) {
        int i0 = t, i1 = t + 1024;
        float2 w = tw[t];
        float2 u = data[PAD(i0)];
        float2 v = data[PAD(i1)];
        float2 wv = cmul(w, v);
        data[PAD(i0)] = make_float2(u.x + wv.x, u.y + wv.y);
        data[PAD(i1)] = make_float2(u.x - wv.x, u.y - wv.y);
    }
    __syncthreads();

    // real-split postprocess -> X[0..2048], parity-trick twiddle, float2 store
    float2* So = (float2*)(S + (size_t)bm * NBINS * 2);
    for (int k = tid; k < NBINS; k += 512) {
        float2 Zk = data[PAD(k & (NH - 1))];
        float2 Zm = data[PAD((NH - k) & (NH - 1))];
        float er = 0.5f * (Zk.x + Zm.x);
        float ei = 0.5f * (Zk.y - Zm.y);
        float dr = Zk.x - Zm.x;
        float di = Zk.y + Zm.y;
        float orr = 0.5f * di;       // O = -i*d/2
        float oii = -0.5f * dr;
        float2 W;
        if (k == 2048) {
            W = make_float2(-1.0f, 0.0f);
        } else {
            float2 t = tw[k >> 1];
            if (k & 1) W = make_float2(t.x * CQ + t.y * SQ,
                                       t.y * CQ - t.x * SQ);
            else       W = t;
        }
        So[k] = make_float2(er + W.x * orr - W.y * oii,
                            ei + W.x * oii + W.y * orr);
    }
}

// ---------------------------------------------------------------------------
// Kernel 2: per (b,p,seg): PHAT (irfft weight folded) for 256(+1) bins into
// LDS, then lag partials via n/-n symmetry; fp32 atomicAdd into cc.
// (No fences, no cross-block protocols — R5/R9/R11 lesson, reconfirmed by
// this session's R1 coop (-100us) and R2 fence-fusion (-12us) attempts.)
// ---------------------------------------------------------------------------
#define NCH 6
#define CHLEN 43
__global__ __launch_bounds__(256)
void phat_cc_kernel(const float* __restrict__ S,
                    const int* __restrict__ comb,
                    float* __restrict__ cc, int P) {
    int id  = (int)blockIdx.x;
    int seg = id & (NSEG - 1);
    int bp  = id >> 3;
    int b   = bp / P;
    int p   = bp % P;
    int ma = comb[p * 2 + 0];
    int mb = comb[p * 2 + 1];
    const float2* Sa = (const float2*)(S + ((size_t)(b * 8 + ma)) * NBINS * 2);
    const float2* Sb = (const float2*)(S + ((size_t)(b * 8 + mb)) * NBINS * 2);

    int k0 = seg * SEGLEN;
    int k1 = (seg == NSEG - 1) ? NBINS : (k0 + SEGLEN);   // last seg: 257 bins

    __shared__ float2 phs[SEGLEN + 1];       // 2,056 B
    __shared__ float partCr[41 * NCH];       //   984 B
    __shared__ float partCi[41 * NCH];

    int tid = (int)threadIdx.x;
    for (int k = k0 + tid; k < k1; k += 256) {
        float2 a = Sa[k];
        float2 c = Sb[k];
        float Xr = a.x * c.x + a.y * c.y;     // Sa * conj(Sb)
        float Xi = a.y * c.x - a.x * c.y;
        float mag = sqrtf(Xr * Xr + Xi * Xi);
        float w = (k == 0 || k == 2048) ? 1.0f : 2.0f;
        float inv = w / (mag + 1e-12f);
        phs[k - k0] = make_float2(Xr * inv, Xi * inv);
    }
    __syncthreads();

    if (tid < 41 * NCH) {
        int n = tid % 41;                      // |lag| 0..40
        int c = tid / 41;
        int kk0 = k0 + c * CHLEN;
        int kk1 = kk0 + CHLEN;
        if (kk1 > k1) kk1 = k1;

        float step = (2.0f * PI_F / (float)N_FFT) * (float)n;
        float sv, cv;
        sincosf(step, &sv, &cv);
        float wr = cv, wi = sv;               // e^{+i step}
        sincosf(step * (float)kk0, &sv, &cv);
        float rr = cv, ri = sv;               // e^{+i step kk0}

        float Cr = 0.0f, Ci = 0.0f;
        for (int k = kk0; k < kk1; ++k) {
            float2 ph = phs[k - k0];
            Cr = fmaf(ph.x, rr, Cr);
            Ci = fmaf(ph.y, ri, Ci);
            float nr = rr * wr - ri * wi;
            float ni = rr * wi + ri * wr;
            rr = nr; ri = ni;
        }
        partCr[tid] = Cr;
        partCi[tid] = Ci;
    }
    __syncthreads();

    if (tid < 41) {
        float Cr = 0.0f, Ci = 0.0f;
        #pragma unroll
        for (int c = 0; c < NCH; ++c) {
            Cr += partCr[tid + 41 * c];
            Ci += partCi[tid + 41 * c];
        }
        float* outp = cc + (size_t)bp * NLAGS;
        atomicAdd(&outp[MAXTAU + tid], Cr - Ci);
        if (tid > 0) atomicAdd(&outp[MAXTAU - tid], Cr + Ci);
    }
}

// ---------------------------------------------------------------------------
// Kernel 3: grid = (chunk, batch), 512 threads (512 grid points per block:
// halves cc-staging traffic vs 256). cc[b] staged via float4; per-thread
// power; wave-shuffle argmax (ties -> lowest index, matching np.argmax).
// Plain stores of block results (NO fence, NO last-block fusion).
// ---------------------------------------------------------------------------
__global__ __launch_bounds__(512)
void power_argmax_kernel(const float* __restrict__ cc,
                         const int* __restrict__ tau,
                         int G, int P,
                         float* __restrict__ pval,
                         int* __restrict__ pidx, int nchunks) {
    int b     = (int)blockIdx.y;
    int chunk = (int)blockIdx.x;
    int tid   = (int)threadIdx.x;

    __shared__ float ccs[28 * NLAGS];   // 9,072 B (2268 floats = 567 float4)
    const float4* csrc = (const float4*)(cc + (size_t)b * P * NLAGS);
    float4* cdst = (float4*)ccs;
    const float scale = 1.0f / (float)N_FFT;
    for (int i = tid; i < 28 * NLAGS / 4; i += 512) {
        float4 v = csrc[i];
        cdst[i] = make_float4(v.x * scale, v.y * scale, v.z * scale, v.w * scale);
    }
    __syncthreads();

    int g = chunk * 512 + tid;
    float v = -1e30f;
    int   gi = 0x7fffffff;
    if (g < G) {
        const int4* tp = (const int4*)(tau + (size_t)g * 28);
        v = 0.0f;
        #pragma unroll
        for (int q = 0; q < 7; ++q) {
            int4 tv = tp[q];
            v += ccs[(q * 4 + 0) * NLAGS + tv.x];
            v += ccs[(q * 4 + 1) * NLAGS + tv.y];
            v += ccs[(q * 4 + 2) * NLAGS + tv.z];
            v += ccs[(q * 4 + 3) * NLAGS + tv.w];
        }
        gi = g;
    }

    #pragma unroll
    for (int off = 32; off > 0; off >>= 1) {
        float v2 = __shfl_down(v, off);
        int   i2 = __shfl_down(gi, off);
        if (v2 > v || (v2 == v && i2 < gi)) { v = v2; gi = i2; }
    }
    __shared__ float wval[8];
    __shared__ int   widx[8];
    int lane = tid & 63, wv = tid >> 6;
    if (lane == 0) { wval[wv] = v; widx[wv] = gi; }
    __syncthreads();
    if (tid == 0) {
        #pragma unroll
        for (int w = 1; w < 8; ++w) {
            float v2 = wval[w]; int i2 = widx[w];
            if (v2 > v || (v2 == v && i2 < gi)) { v = v2; gi = i2; }
        }
        pval[b * nchunks + chunk] = v;
        pidx[b * nchunks + chunk] = gi;
    }
}

// ---------------------------------------------------------------------------
// Kernel 4: final reduction over chunks (one block per batch, one wave).
// ---------------------------------------------------------------------------
__global__ void finalize_kernel(const float* __restrict__ pval,
                                const int* __restrict__ pidx, int nchunks,
                                const float* __restrict__ grid_x,
                                const float* __restrict__ rec_centroid,
                                float* __restrict__ out) {
    int b = (int)blockIdx.x;
    int l = (int)threadIdx.x;
    float v = -1e30f; int gi = 0x7fffffff;
    for (int j = l; j < nchunks; j += 64) {
        float v2 = pval[b * nchunks + j];
        int   i2 = pidx[b * nchunks + j];
        if (v2 > v || (v2 == v && i2 < gi)) { v = v2; gi = i2; }
    }
    #pragma unroll
    for (int off = 32; off > 0; off >>= 1) {
        float v2 = __shfl_down(v, off);
        int   i2 = __shfl_down(gi, off);
        if (v2 > v || (v2 == v && i2 < gi)) { v = v2; gi = i2; }
    }
    if (l == 0) {
        for (int c = 0; c < 3; ++c)
            out[b * 3 + c] = grid_x[(size_t)gi * 3 + c] - rec_centroid[c];
    }
}

extern "C" void kernel_launch(void* const* d_in, const int* in_sizes, int n_in,
                              void* d_out, int out_size, void* d_ws, size_t ws_size,
                              hipStream_t stream) {
    const float* signal       = (const float*)d_in[0];
    const float* grid_x       = (const float*)d_in[1];
    const int*   tau          = (const int*)d_in[2];
    const int*   comb         = (const int*)d_in[3];
    const float* rec_centroid = (const float*)d_in[4];
    float* out = (float*)d_out;

    int G  = in_sizes[1] / 3;          // ~31416 grid points
    int P  = in_sizes[3] / 2;          // 28 pairs
    int BM = in_sizes[0] / N_FFT;      // 128 channels
    int B  = BM / 8;                   // 16 batches
    int BP = B * P;                    // 448

    // workspace layout (16B-aligned throughout: offsets are multiples of 16)
    float* S  = (float*)d_ws;                      // BM*2049*2 floats (2.1 MB)
    float* cc = S + (size_t)BM * NBINS * 2;        // BP*81 floats
    int nchunks = (G + 511) / 512;
    float* pval = cc + (size_t)BP * NLAGS;
    int*   pidx = (int*)(pval + (size_t)B * nchunks);

    rfft_kernel<<<BM, 512, 0, stream>>>(signal, S, cc, BP * NLAGS);
    phat_cc_kernel<<<BP * NSEG, 256, 0, stream>>>(S, comb, cc, P);
    power_argmax_kernel<<<dim3(nchunks, B), 512, 0, stream>>>(cc, tau, G, P, pval, pidx, nchunks);
    finalize_kernel<<<B, 64, 0, stream>>>(pval, pidx, nchunks, grid_x, rec_centroid, out);
}